// Round 2
// baseline (1664.288 us; speedup 1.0000x reference)
//
#include <hip/hip_runtime.h>
#include <math.h>

// Problem constants
#define BB 65536
#define II 512
#define HH 128
#define TT 2
#define ES 2
#define EC 4
#define NS 6            // expert slots per task (ES + EC)
#define NJ 12           // per task: 6 gate-logit cols + 6 s-value cols
#define NCOL 24         // TT * NJ
#define FF (NS * HH)    // 768 gate-input features per task

// ---------------------------------------------------------------------------
// Kernel 1: fold all weights into M[II][NCOL] and d[NCOL].
// Grid: 65 blocks x 256 thr. Blocks 0..63 -> 8 i-rows each; block 64 -> d[].
// Stage W-slab + Wg + Wt in LDS (coalesced), compute 24 cols from LDS.
// ---------------------------------------------------------------------------
#define PI 8                 // i-rows per block
#define XSTR (TT * FF + 8)   // 1544: pad so il-groups land on distinct banks

__global__ __launch_bounds__(256) void cgc_precompute(
    const float* __restrict__ Wc, const float* __restrict__ bc,
    const float* __restrict__ Ws, const float* __restrict__ bs,
    const float* __restrict__ Wg, const float* __restrict__ bg,
    const float* __restrict__ Wt,
    float* __restrict__ M, float* __restrict__ d)
{
    __shared__ float xw[PI * XSTR];        // 49.4 KB
    __shared__ float wg[TT * FF * NS];     // 36.9 KB
    __shared__ float wt[TT * HH];          // 1 KB

    const int blk = blockIdx.x;
    const bool isd = (blk == II / PI);     // block 64: bias row
    const int i0  = blk * PI;
    const int tid = threadIdx.x;

    // Stage Wg, Wt (coalesced, contiguous)
    for (int idx = tid; idx < TT * FF * NS; idx += 256) wg[idx] = Wg[idx];
    if (tid < TT * HH) wt[tid] = Wt[tid];

    // Stage W-slab (or bias vector) into xw
    const int nload = isd ? (TT * FF) : (PI * TT * FF);
    for (int idx = tid; idx < nload; idx += 256) {
        const int il  = idx / (TT * FF);
        const int rem = idx % (TT * FF);
        const int t   = rem / FF;
        const int f   = rem % FF;
        const int s   = f >> 7;            // slot 0..5
        const int h   = f & 127;
        float v;
        if (isd) {
            v = (s < ES) ? bs[(t * ES + s) * HH + h]
                         : bc[(s - ES) * HH + h];
        } else {
            const int i = i0 + il;
            v = (s < ES) ? Ws[(((t * ES + s) * II) + i) * HH + h]
                         : Wc[(((s - ES) * II) + i) * HH + h];
        }
        xw[il * XSTR + rem] = v;
    }
    __syncthreads();

    const int nout = isd ? NCOL : (PI * NCOL);
    if (tid < nout) {
        const int il  = tid / NCOL;
        const int col = tid % NCOL;
        const int t   = col / NJ;
        const int j   = col % NJ;
        const float* xr = &xw[il * XSTR + t * FF];
        float acc = 0.0f;
        if (j < NS) {
            const float* wgr = &wg[t * FF * NS + j];
            #pragma unroll 8
            for (int f = 0; f < FF; ++f)
                acc = fmaf(xr[f], wgr[f * NS], acc);
        } else {
            const int s = j - NS;
            const float* xs = xr + s * HH;
            const float* wtr = &wt[t * HH];
            #pragma unroll 8
            for (int h = 0; h < HH; ++h)
                acc = fmaf(xs[h], wtr[h], acc);
        }
        if (isd) {
            if (j < NS) acc += bg[t * NS + j];
            d[col] = acc;
        } else {
            M[(i0 + il) * NCOL + col] = acc;
        }
    }
}

// ---------------------------------------------------------------------------
// Kernel 2: out[t*B + b] = softmax(z[0:6]) . z[6:12] + bt[t],  z = x@M + d
// 256 thr / block (4 waves), 64 rows / block, K split 4-ways across waves.
// Each wave: barrier-free LDS transpose staging of its K-range (chunks of 32),
// M read via wave-uniform addresses (scalar loads). Final: LDS reduction of
// z-partials, epilogue by wave 0. 4096 waves total -> 16 waves/CU.
// ---------------------------------------------------------------------------
#define ROWS 64
#define WV 4
#define KW (II / WV)        // 128 K per wave
#define KC 32
#define NCHUNK (KW / KC)    // 4
#define LPAD (ROWS + 1)     // 65
#define ZPAD 25

union MainSh {
    float tile[WV][KC][LPAD];   // 33.3 KB
    float zbuf[WV][ROWS][ZPAD]; // 25.6 KB
};

__global__ __launch_bounds__(256, 4) void cgc_main(
    const float* __restrict__ x,
    const float* __restrict__ Mg,
    const float* __restrict__ dg,
    const float* __restrict__ bt,
    float* __restrict__ out)
{
    __shared__ MainSh sh;

    const int tid  = threadIdx.x;
    const int w    = tid >> 6;       // wave 0..3
    const int lane = tid & 63;       // row within block
    const int r0   = blockIdx.x * ROWS;
    const int row  = r0 + lane;
    const int lr   = lane >> 3;      // staging base row 0..7
    const int lk   = (lane & 7) * 4; // staging k offset (floats)
    const int kw0  = w * KW;

    const float4* xv = (const float4*)x;
    float4 pre[8];

    auto load_chunk = [&](int c) {
        const int kbase = kw0 + c * KC + lk;
        #pragma unroll
        for (int it = 0; it < 8; ++it) {
            const int rr = r0 + lr + it * 8;
            pre[it] = xv[(rr * II + kbase) >> 2];
        }
    };
    auto store_chunk = [&]() {
        #pragma unroll
        for (int it = 0; it < 8; ++it) {
            const int rr = lr + it * 8;
            sh.tile[w][lk + 0][rr] = pre[it].x;
            sh.tile[w][lk + 1][rr] = pre[it].y;
            sh.tile[w][lk + 2][rr] = pre[it].z;
            sh.tile[w][lk + 3][rr] = pre[it].w;
        }
    };

    float z[NCOL];
    #pragma unroll
    for (int j = 0; j < NCOL; ++j) z[j] = (w == 0) ? dg[j] : 0.0f;

    load_chunk(0);
    store_chunk();
    __builtin_amdgcn_wave_barrier();

    for (int c = 0; c < NCHUNK; ++c) {
        if (c + 1 < NCHUNK) load_chunk(c + 1);

        float xl[KC];
        #pragma unroll
        for (int k = 0; k < KC; ++k) xl[k] = sh.tile[w][k][lane];

        #pragma unroll
        for (int k = 0; k < KC; ++k) {
            const float* Mr = &Mg[(kw0 + c * KC + k) * NCOL];  // wave-uniform
            #pragma unroll
            for (int j = 0; j < NCOL; ++j)
                z[j] = fmaf(xl[k], Mr[j], z[j]);
        }

        __builtin_amdgcn_wave_barrier();
        if (c + 1 < NCHUNK) {
            store_chunk();
            __builtin_amdgcn_wave_barrier();
        }
    }

    // Cross-wave reduction of z partials
    __syncthreads();                 // all tile reads done before zbuf aliases
    if (w > 0) {
        #pragma unroll
        for (int j = 0; j < NCOL; ++j) sh.zbuf[w][lane][j] = z[j];
    }
    __syncthreads();

    if (w == 0) {
        #pragma unroll
        for (int ww = 1; ww < WV; ++ww)
            #pragma unroll
            for (int j = 0; j < NCOL; ++j)
                z[j] += sh.zbuf[ww][lane][j];

        // Epilogue: per-task softmax(6) + weighted sum of s-values
        #pragma unroll
        for (int t = 0; t < TT; ++t) {
            const int base = t * NJ;
            float m = z[base + 0];
            #pragma unroll
            for (int j = 1; j < NS; ++j) m = fmaxf(m, z[base + j]);
            float s = 0.0f, o = 0.0f;
            #pragma unroll
            for (int j = 0; j < NS; ++j) {
                const float e = __expf(z[base + j] - m);
                s += e;
                o += e * z[base + NS + j];
            }
            out[t * BB + row] = o / s + bt[t];
        }
    }
}

// ---------------------------------------------------------------------------
extern "C" void kernel_launch(void* const* d_in, const int* in_sizes, int n_in,
                              void* d_out, int out_size, void* d_ws, size_t ws_size,
                              hipStream_t stream)
{
    const float* x  = (const float*)d_in[0];
    const float* Wc = (const float*)d_in[1];
    const float* bc = (const float*)d_in[2];
    const float* Ws = (const float*)d_in[3];
    const float* bs = (const float*)d_in[4];
    const float* Wg = (const float*)d_in[5];
    const float* bg = (const float*)d_in[6];
    const float* Wt = (const float*)d_in[7];
    const float* bt = (const float*)d_in[8];
    float* out = (float*)d_out;

    float* M = (float*)d_ws;            // [II][NCOL]
    float* d = M + II * NCOL;           // [NCOL]

    cgc_precompute<<<dim3(II / PI + 1), dim3(256), 0, stream>>>(
        Wc, bc, Ws, bs, Wg, bg, Wt, M, d);
    cgc_main<<<dim3(BB / ROWS), dim3(256), 0, stream>>>(
        x, M, d, bt, out);
}

// Round 3
// 972.932 us; speedup vs baseline: 1.7106x; 1.7106x over previous
//
#include <hip/hip_runtime.h>
#include <math.h>

// Problem constants
#define BB 65536
#define II 512
#define HH 128
#define TT 2
#define ES 2
#define EC 4
#define NS 6            // expert slots per task (ES + EC)
#define NJ 12           // per task: 6 gate-logit cols + 6 s-value cols
#define NCOL 24         // TT * NJ
#define FF (NS * HH)    // 768 gate-input features per task

// ---------------------------------------------------------------------------
// Kernel 1: fold all weights into M[II][NCOL] and d[NCOL].
// Grid: II+1 thin blocks (one per i-row; block II = bias row), 256 threads.
// Stage the 1536-float W-row in LDS (coalesced), split each column's dot
// product 8 ways across threads, LDS tree-reduce. 2052 waves total.
// ---------------------------------------------------------------------------
__global__ __launch_bounds__(256) void cgc_precompute(
    const float* __restrict__ Wc, const float* __restrict__ bc,
    const float* __restrict__ Ws, const float* __restrict__ bs,
    const float* __restrict__ Wg, const float* __restrict__ bg,
    const float* __restrict__ Wt,
    float* __restrict__ M, float* __restrict__ d)
{
    __shared__ float wrow[TT * FF];   // 6 KB
    __shared__ float red[NCOL][9];

    const int blk = blockIdx.x;
    const bool isd = (blk == II);
    const int i   = blk;
    const int tid = threadIdx.x;

    // Stage W-row (or bias vector) into LDS, coalesced 128-float segments.
    for (int idx = tid; idx < TT * FF; idx += 256) {
        const int t = idx / FF;
        const int f = idx % FF;
        const int s = f >> 7;
        const int h = f & 127;
        float v;
        if (isd) {
            v = (s < ES) ? bs[(t * ES + s) * HH + h]
                         : bc[(s - ES) * HH + h];
        } else {
            v = (s < ES) ? Ws[(((t * ES + s) * II) + i) * HH + h]
                         : Wc[(((s - ES) * II) + i) * HH + h];
        }
        wrow[idx] = v;
    }
    __syncthreads();

    // 192 active threads: col = tid/8 (0..23), fp = tid%8 (f-partition)
    const int col = tid >> 3;
    const int fp  = tid & 7;
    if (col < NCOL) {
        const int t = col / NJ;
        const int j = col % NJ;
        float acc = 0.0f;
        if (j < NS) {
            const float* wr = &wrow[t * FF];
            const int f0 = fp * 96;
            #pragma unroll 8
            for (int ff = f0; ff < f0 + 96; ++ff)
                acc = fmaf(wr[ff], Wg[(t * FF + ff) * NS + j], acc);
        } else {
            const int s = j - NS;
            const float* wr = &wrow[t * FF + s * HH];
            const int h0 = fp * 16;
            #pragma unroll
            for (int hh = h0; hh < h0 + 16; ++hh)
                acc = fmaf(wr[hh], Wt[t * HH + hh], acc);
        }
        red[col][fp] = acc;
    }
    __syncthreads();

    if (tid < NCOL) {
        float v = 0.0f;
        #pragma unroll
        for (int p = 0; p < 8; ++p) v += red[tid][p];
        const int t = tid / NJ, j = tid % NJ;
        if (isd) {
            if (j < NS) v += bg[t * NS + j];
            d[tid] = v;
        } else {
            M[i * NCOL + tid] = v;
        }
    }
}

// ---------------------------------------------------------------------------
// Kernel 2: out[t*B + b] = softmax(z[0:6]) . z[6:12] + bt[t],  z = x@M + d
// 256 thr (4 waves) / block, 64 rows / block, K split 4 ways across waves.
// Per-wave LDS transpose staging (chunks of 32 k), M read via wave-uniform
// addresses (SMEM scalar loads). Cross-wave z-reduction in LDS, epilogue by
// wave 0. 1024 blocks -> 4096 waves -> 16 waves/CU. NO min-waves bound (the
// R2 VGPR=64 cap caused 4.7 GB of scratch spill traffic).
// ---------------------------------------------------------------------------
#define ROWS 64
#define WV 4
#define KW (II / WV)        // 128 K per wave
#define KC 32
#define NCHUNK (KW / KC)    // 4
#define LPAD (ROWS + 1)     // 65
#define ZPAD 25

union MainSh {
    float tile[WV][KC][LPAD];   // 33.3 KB
    float zbuf[WV][ROWS][ZPAD]; // 25.6 KB
};

__global__ __launch_bounds__(256) void cgc_main(
    const float* __restrict__ x,
    const float* __restrict__ Mg,
    const float* __restrict__ dg,
    const float* __restrict__ bt,
    float* __restrict__ out)
{
    __shared__ MainSh sh;

    const int tid  = threadIdx.x;
    const int w    = tid >> 6;       // wave 0..3
    const int lane = tid & 63;       // row within block
    const int r0   = blockIdx.x * ROWS;
    const int row  = r0 + lane;
    const int lr   = lane >> 3;      // staging base row 0..7
    const int lk   = (lane & 7) * 4; // staging k offset (floats)
    const int kw0  = w * KW;

    const float4* xv = (const float4*)x;
    float4 pre[8];

    auto load_chunk = [&](int c) {
        const int kbase = kw0 + c * KC + lk;
        #pragma unroll
        for (int it = 0; it < 8; ++it) {
            const int rr = r0 + lr + it * 8;
            pre[it] = xv[(rr * II + kbase) >> 2];
        }
    };
    auto store_chunk = [&]() {
        #pragma unroll
        for (int it = 0; it < 8; ++it) {
            const int rr = lr + it * 8;
            sh.tile[w][lk + 0][rr] = pre[it].x;
            sh.tile[w][lk + 1][rr] = pre[it].y;
            sh.tile[w][lk + 2][rr] = pre[it].z;
            sh.tile[w][lk + 3][rr] = pre[it].w;
        }
    };

    float z[NCOL];
    #pragma unroll
    for (int j = 0; j < NCOL; ++j) z[j] = (w == 0) ? dg[j] : 0.0f;

    load_chunk(0);
    store_chunk();
    __builtin_amdgcn_wave_barrier();

    for (int c = 0; c < NCHUNK; ++c) {
        if (c + 1 < NCHUNK) load_chunk(c + 1);   // overlap with compute

        #pragma unroll
        for (int k = 0; k < KC; ++k) {
            const float xk = sh.tile[w][k][lane];            // ds_read_b32
            const float* Mr = &Mg[(kw0 + c * KC + k) * NCOL]; // wave-uniform
            #pragma unroll
            for (int j = 0; j < NCOL; ++j)
                z[j] = fmaf(xk, Mr[j], z[j]);
        }

        __builtin_amdgcn_wave_barrier();
        if (c + 1 < NCHUNK) {
            store_chunk();
            __builtin_amdgcn_wave_barrier();
        }
    }

    // Cross-wave reduction of z partials (zbuf aliases tile: sync first)
    __syncthreads();
    if (w > 0) {
        #pragma unroll
        for (int j = 0; j < NCOL; ++j) sh.zbuf[w][lane][j] = z[j];
    }
    __syncthreads();

    if (w == 0) {
        #pragma unroll
        for (int ww = 1; ww < WV; ++ww)
            #pragma unroll
            for (int j = 0; j < NCOL; ++j)
                z[j] += sh.zbuf[ww][lane][j];

        // Epilogue: per-task softmax(6) + weighted sum of s-values
        #pragma unroll
        for (int t = 0; t < TT; ++t) {
            const int base = t * NJ;
            float m = z[base + 0];
            #pragma unroll
            for (int j = 1; j < NS; ++j) m = fmaxf(m, z[base + j]);
            float s = 0.0f, o = 0.0f;
            #pragma unroll
            for (int j = 0; j < NS; ++j) {
                const float e = __expf(z[base + j] - m);
                s += e;
                o += e * z[base + NS + j];
            }
            out[t * BB + row] = o / s + bt[t];
        }
    }
}

// ---------------------------------------------------------------------------
extern "C" void kernel_launch(void* const* d_in, const int* in_sizes, int n_in,
                              void* d_out, int out_size, void* d_ws, size_t ws_size,
                              hipStream_t stream)
{
    const float* x  = (const float*)d_in[0];
    const float* Wc = (const float*)d_in[1];
    const float* bc = (const float*)d_in[2];
    const float* Ws = (const float*)d_in[3];
    const float* bs = (const float*)d_in[4];
    const float* Wg = (const float*)d_in[5];
    const float* bg = (const float*)d_in[6];
    const float* Wt = (const float*)d_in[7];
    const float* bt = (const float*)d_in[8];
    float* out = (float*)d_out;

    float* M = (float*)d_ws;            // [II][NCOL]
    float* d = M + II * NCOL;           // [NCOL]

    cgc_precompute<<<dim3(II + 1), dim3(256), 0, stream>>>(
        Wc, bc, Ws, bs, Wg, bg, Wt, M, d);
    cgc_main<<<dim3(BB / ROWS), dim3(256), 0, stream>>>(
        x, M, d, bt, out);
}

// Round 4
// 231.125 us; speedup vs baseline: 7.2008x; 4.2096x over previous
//
#include <hip/hip_runtime.h>
#include <math.h>

// Problem constants
#define BB 65536
#define II 512
#define HH 128
#define TT 2
#define ES 2
#define EC 4
#define NS 6            // expert slots per task (ES + EC)
#define NJ 12           // per task: 6 gate-logit cols + 6 s-value cols
#define NCOL 24         // TT * NJ
#define FF (NS * HH)    // 768 gate-input features per task

// ---------------------------------------------------------------------------
// Kernel 1: fold all weights into M[II][NCOL] and d[NCOL].
// Grid: II+1 thin blocks (one per i-row; block II = bias row), 256 threads.
// Stage W-row + ALL of Wg + Wt into LDS with coalesced float4 loads, then the
// 96-MAC per-thread dot products run entirely out of LDS (R3's version did
// 24-line global gathers on Wg each iteration -> latency-bound).
// ---------------------------------------------------------------------------
#define PF 8

__global__ __launch_bounds__(256) void cgc_precompute(
    const float* __restrict__ Wc, const float* __restrict__ bc,
    const float* __restrict__ Ws, const float* __restrict__ bs,
    const float* __restrict__ Wg, const float* __restrict__ bg,
    const float* __restrict__ Wt,
    float* __restrict__ M, float* __restrict__ d)
{
    __shared__ float wrow[TT * FF];        // 6 KB
    __shared__ float wg[TT * FF * NS];     // 36.9 KB
    __shared__ float wt[TT * HH];          // 1 KB
    __shared__ float red[NCOL][PF + 1];

    const int blk = blockIdx.x;
    const bool isd = (blk == II);
    const int i   = blk;
    const int tid = threadIdx.x;

    // Stage Wg (9216 floats = 2304 float4), Wt (64 float4) — coalesced.
    {
        const float4* Wg4 = (const float4*)Wg;
        float4* wg4 = (float4*)wg;
        for (int idx = tid; idx < TT * FF * NS / 4; idx += 256)
            wg4[idx] = Wg4[idx];
        if (tid < TT * HH / 4)
            ((float4*)wt)[tid] = ((const float4*)Wt)[tid];
    }
    // Stage W-row (or bias vector): 384 float4.
    {
        const float4* Ws4 = (const float4*)Ws;
        const float4* Wc4 = (const float4*)Wc;
        const float4* bs4 = (const float4*)bs;
        const float4* bc4 = (const float4*)bc;
        float4* wr4 = (float4*)wrow;
        for (int idx = tid; idx < TT * FF / 4; idx += 256) {
            const int t   = idx / (FF / 4);
            const int rem = idx % (FF / 4);      // 0..191
            const int s   = rem >> 5;            // slot 0..5
            const int h4  = rem & 31;            // float4 within 128-h row
            float4 v;
            if (isd) {
                v = (s < ES) ? bs4[(t * ES + s) * 32 + h4]
                             : bc4[(s - ES) * 32 + h4];
            } else {
                v = (s < ES) ? Ws4[((t * ES + s) * II + i) * 32 + h4]
                             : Wc4[((s - ES) * II + i) * 32 + h4];
            }
            wr4[idx] = v;
        }
    }
    __syncthreads();

    // 192 active threads: col = tid/8 (0..23), fp = tid%8 (f-partition)
    const int col = tid >> 3;
    const int fp  = tid & 7;
    if (col < NCOL) {
        const int t = col / NJ;
        const int j = col % NJ;
        float acc = 0.0f;
        if (j < NS) {
            const float* wr  = &wrow[t * FF];
            const float* wgr = &wg[t * FF * NS + j];
            const int f0 = fp * 96;
            #pragma unroll 4
            for (int f = f0; f < f0 + 96; ++f)
                acc = fmaf(wr[f], wgr[f * NS], acc);
        } else {
            const int s = j - NS;
            const float* wr  = &wrow[t * FF + s * HH];
            const float* wtr = &wt[t * HH];
            const int h0 = fp * 16;
            #pragma unroll
            for (int h = h0; h < h0 + 16; ++h)
                acc = fmaf(wr[h], wtr[h], acc);
        }
        red[col][fp] = acc;
    }
    __syncthreads();

    if (tid < NCOL) {
        float v = 0.0f;
        #pragma unroll
        for (int p = 0; p < PF; ++p) v += red[tid][p];
        const int t = tid / NJ, j = tid % NJ;
        if (isd) {
            if (j < NS) v += bg[t * NS + j];
            d[tid] = v;
        } else {
            M[i * NCOL + tid] = v;
        }
    }
}

// ---------------------------------------------------------------------------
// Kernel 2: out[t*B + b] = softmax(z[0:6]) . z[6:12] + bt[t],  z = x@M + d
// 256 thr (4 waves) / block, 64 rows / block, K split 4 ways across waves.
// Per-wave LDS staging of BOTH the x transpose tile AND the M chunk (R3's
// direct global M loads either serialized at L2 latency (R1, VGPR=60) or
// spilled when hoisted (R3, VGPR=256)). M is read back as uniform-address
// ds_read_b128 (broadcast, conflict-free, no VGPR hoisting pressure).
// 1024 blocks -> 4096 waves -> 16 waves/CU.
// ---------------------------------------------------------------------------
#define ROWS 64
#define WV 4
#define KW (II / WV)        // 128 K per wave
#define KC 32
#define NCHUNK (KW / KC)    // 4
#define LPAD (ROWS + 1)     // 65
#define ZPAD 25
#define MCH (KC * NCOL)     // 768 floats per M chunk

union MainSh {
    float tile[WV][KC][LPAD];   // 33.3 KB
    float zbuf[WV][ROWS][ZPAD]; // 25.6 KB
};

__global__ __launch_bounds__(256) void cgc_main(
    const float* __restrict__ x,
    const float* __restrict__ Mg,
    const float* __restrict__ dg,
    const float* __restrict__ bt,
    float* __restrict__ out)
{
    __shared__ MainSh sh;
    __shared__ float mt[WV][MCH];   // 12 KB

    const int tid  = threadIdx.x;
    const int w    = tid >> 6;       // wave 0..3
    const int lane = tid & 63;       // row within block
    const int r0   = blockIdx.x * ROWS;
    const int row  = r0 + lane;
    const int lr   = lane >> 3;      // staging base row 0..7
    const int lk   = (lane & 7) * 4; // staging k offset (floats)
    const int kw0  = w * KW;

    const float4* xv = (const float4*)x;
    const float4* mg4 = (const float4*)Mg;
    float4 pre[8];
    float4 mpre[3];

    auto load_chunk = [&](int c) {
        const int kbase = kw0 + c * KC + lk;
        #pragma unroll
        for (int it = 0; it < 8; ++it) {
            const int rr = r0 + lr + it * 8;
            pre[it] = xv[(rr * II + kbase) >> 2];
        }
        // M chunk: rows [kw0+c*KC, +KC) -> 192 float4, 3 per lane, coalesced
        const int mb4 = (kw0 + c * KC) * (NCOL / 4);
        #pragma unroll
        for (int r = 0; r < 3; ++r)
            mpre[r] = mg4[mb4 + r * 64 + lane];
    };
    auto store_chunk = [&]() {
        #pragma unroll
        for (int it = 0; it < 8; ++it) {
            const int rr = lr + it * 8;
            sh.tile[w][lk + 0][rr] = pre[it].x;
            sh.tile[w][lk + 1][rr] = pre[it].y;
            sh.tile[w][lk + 2][rr] = pre[it].z;
            sh.tile[w][lk + 3][rr] = pre[it].w;
        }
        float4* m4 = (float4*)&mt[w][0];
        #pragma unroll
        for (int r = 0; r < 3; ++r)
            m4[r * 64 + lane] = mpre[r];
    };

    float z[NCOL];
    #pragma unroll
    for (int j = 0; j < NCOL; ++j) z[j] = (w == 0) ? dg[j] : 0.0f;

    load_chunk(0);
    store_chunk();
    __builtin_amdgcn_wave_barrier();

    #pragma unroll 1
    for (int c = 0; c < NCHUNK; ++c) {
        if (c + 1 < NCHUNK) load_chunk(c + 1);   // overlap with compute

        #pragma unroll 2
        for (int k = 0; k < KC; ++k) {
            const float xk = sh.tile[w][k][lane];        // ds_read_b32
            const float4* mr = (const float4*)&mt[w][k * NCOL]; // uniform
            #pragma unroll
            for (int jq = 0; jq < 6; ++jq) {
                const float4 mv = mr[jq];                // ds_read_b128 bcast
                z[jq * 4 + 0] = fmaf(xk, mv.x, z[jq * 4 + 0]);
                z[jq * 4 + 1] = fmaf(xk, mv.y, z[jq * 4 + 1]);
                z[jq * 4 + 2] = fmaf(xk, mv.z, z[jq * 4 + 2]);
                z[jq * 4 + 3] = fmaf(xk, mv.w, z[jq * 4 + 3]);
            }
        }

        __builtin_amdgcn_wave_barrier();
        if (c + 1 < NCHUNK) {
            store_chunk();
            __builtin_amdgcn_wave_barrier();
        }
    }

    // Cross-wave reduction of z partials (zbuf aliases tile: sync first)
    __syncthreads();
    if (w > 0) {
        #pragma unroll
        for (int j = 0; j < NCOL; ++j) sh.zbuf[w][lane][j] = z[j];
    }
    __syncthreads();

    if (w == 0) {
        #pragma unroll
        for (int ww = 1; ww < WV; ++ww)
            #pragma unroll
            for (int j = 0; j < NCOL; ++j)
                z[j] += sh.zbuf[ww][lane][j];

        // Epilogue: per-task softmax(6) + weighted sum of s-values
        #pragma unroll
        for (int t = 0; t < TT; ++t) {
            const int base = t * NJ;
            float m = z[base + 0];
            #pragma unroll
            for (int j = 1; j < NS; ++j) m = fmaxf(m, z[base + j]);
            float s = 0.0f, o = 0.0f;
            #pragma unroll
            for (int j = 0; j < NS; ++j) {
                const float e = __expf(z[base + j] - m);
                s += e;
                o += e * z[base + NS + j];
            }
            out[t * BB + row] = o / s + bt[t];
        }
    }
}

// ---------------------------------------------------------------------------
extern "C" void kernel_launch(void* const* d_in, const int* in_sizes, int n_in,
                              void* d_out, int out_size, void* d_ws, size_t ws_size,
                              hipStream_t stream)
{
    const float* x  = (const float*)d_in[0];
    const float* Wc = (const float*)d_in[1];
    const float* bc = (const float*)d_in[2];
    const float* Ws = (const float*)d_in[3];
    const float* bs = (const float*)d_in[4];
    const float* Wg = (const float*)d_in[5];
    const float* bg = (const float*)d_in[6];
    const float* Wt = (const float*)d_in[7];
    const float* bt = (const float*)d_in[8];
    float* out = (float*)d_out;

    float* M = (float*)d_ws;            // [II][NCOL]
    float* d = M + II * NCOL;           // [NCOL]

    cgc_precompute<<<dim3(II + 1), dim3(256), 0, stream>>>(
        Wc, bc, Ws, bs, Wg, bg, Wt, M, d);
    cgc_main<<<dim3(BB / ROWS), dim3(256), 0, stream>>>(
        x, M, d, bt, out);
}

// Round 5
// 222.793 us; speedup vs baseline: 7.4701x; 1.0374x over previous
//
#include <hip/hip_runtime.h>
#include <math.h>

// Problem constants
#define BB 65536
#define II 512
#define HH 128
#define TT 2
#define ES 2
#define EC 4
#define NS 6            // expert slots per task (ES + EC)
#define NJ 12           // per task: 6 gate-logit cols + 6 s-value cols
#define NCOL 24         // TT * NJ
#define FF (NS * HH)    // 768 gate-input features per task

// ---------------------------------------------------------------------------
// Kernel 1: fold all weights into M[II][NCOL] and d[NCOL].
// Grid: II+1 thin blocks (one per i-row; block II = bias row), 256 threads.
// Wg staged TRANSPOSED [t][e][f] (pad-4 rows) so the 96-MAC inner loop reads
// consecutive f -> conflict-free (R4 had stride-6 reads = 8-way conflicts).
// f-partition interleaved (f = ff*8+fp) so the 8 fp-lanes never alias mod 32.
// ---------------------------------------------------------------------------
#define FFP (FF + 4)   // 772: padded wgt row

__global__ __launch_bounds__(256) void cgc_precompute(
    const float* __restrict__ Wc, const float* __restrict__ bc,
    const float* __restrict__ Ws, const float* __restrict__ bs,
    const float* __restrict__ Wg, const float* __restrict__ bg,
    const float* __restrict__ Wt,
    float* __restrict__ M, float* __restrict__ d)
{
    __shared__ float wrow[TT * FF];        // 6 KB
    __shared__ float wgt[TT * NS * FFP];   // 37.1 KB  [t][e][f]
    __shared__ float wt[TT * HH];          // 1 KB
    __shared__ float red[NCOL][9];

    const int blk = blockIdx.x;
    const bool isd = (blk == II);
    const int i   = blk;
    const int tid = threadIdx.x;

    // Stage Wg transposed: coalesced float4 global reads, scattered b32 writes
    {
        const float4* Wg4 = (const float4*)Wg;
        for (int idx = tid; idx < TT * FF * NS / 4; idx += 256) {
            const float4 v = Wg4[idx];
            const int p0 = idx * 4;
            const float vv[4] = {v.x, v.y, v.z, v.w};
            #pragma unroll
            for (int u = 0; u < 4; ++u) {
                const int p = p0 + u;               // ((t*FF + f)*NS + e)
                const int t = p / (FF * NS);
                const int r = p % (FF * NS);
                const int f = r / NS;
                const int e = r % NS;
                wgt[(t * NS + e) * FFP + f] = vv[u];
            }
        }
        if (tid < TT * HH / 4)
            ((float4*)wt)[tid] = ((const float4*)Wt)[tid];
    }
    // Stage W-row (or bias vector): 384 float4, coalesced per 32-f4 segment.
    {
        const float4* Ws4 = (const float4*)Ws;
        const float4* Wc4 = (const float4*)Wc;
        const float4* bs4 = (const float4*)bs;
        const float4* bc4 = (const float4*)bc;
        float4* wr4 = (float4*)wrow;
        for (int idx = tid; idx < TT * FF / 4; idx += 256) {
            const int t   = idx / (FF / 4);
            const int rem = idx % (FF / 4);      // 0..191
            const int s   = rem >> 5;            // slot 0..5
            const int h4  = rem & 31;
            float4 v;
            if (isd) {
                v = (s < ES) ? bs4[(t * ES + s) * 32 + h4]
                             : bc4[(s - ES) * 32 + h4];
            } else {
                v = (s < ES) ? Ws4[((t * ES + s) * II + i) * 32 + h4]
                             : Wc4[((s - ES) * II + i) * 32 + h4];
            }
            wr4[idx] = v;
        }
    }
    __syncthreads();

    // 192 active threads: col = tid/8 (0..23), fp = tid%8 (f-partition)
    const int col = tid >> 3;
    const int fp  = tid & 7;
    if (col < NCOL) {
        const int t = col / NJ;
        const int j = col % NJ;
        float acc = 0.0f;
        if (j < NS) {
            const float* wr  = &wrow[t * FF];
            const float* wgr = &wgt[(t * NS + j) * FFP];
            #pragma unroll 4
            for (int ff = 0; ff < FF / 8; ++ff) {
                const int f = ff * 8 + fp;       // interleaved partition
                acc = fmaf(wr[f], wgr[f], acc);
            }
        } else {
            const int s = j - NS;
            const float* wr  = &wrow[t * FF + s * HH];
            const float* wtr = &wt[t * HH];
            #pragma unroll
            for (int hh = 0; hh < HH / 8; ++hh) {
                const int h = hh * 8 + fp;
                acc = fmaf(wr[h], wtr[h], acc);
            }
        }
        red[col][fp] = acc;
    }
    __syncthreads();

    if (tid < NCOL) {
        float v = 0.0f;
        #pragma unroll
        for (int p = 0; p < 8; ++p) v += red[tid][p];
        const int t = tid / NJ, j = tid % NJ;
        if (isd) {
            if (j < NS) v += bg[t * NS + j];
            d[tid] = v;
        } else {
            M[i * NCOL + tid] = v;
        }
    }
}

// ---------------------------------------------------------------------------
// Kernel 2: out[t*B + b] = softmax(z[0:6]) . z[6:12] + bt[t],  z = x@M + d
// 256 thr (4 waves) / block, 64 rows, K split 4 ways across waves. x staged
// via per-wave LDS transpose tile; M read via SCALAR loads (s_load_dwordx8,
// one SGPR operand per v_fmac is free) -- kw0 forced wave-uniform with
// readfirstlane so uniformity analysis fires (R3's tid-derived index made
// the loads divergent -> hoist -> 256-VGPR spill; R4's LDS broadcast made
// the LDS pipe the bottleneck at 6x ds_read_b128 per k). 16 waves/CU.
// ---------------------------------------------------------------------------
#define ROWS 64
#define WV 4
#define KW (II / WV)        // 128 K per wave
#define KC 32
#define NCHUNK (KW / KC)    // 4
#define LPAD (ROWS + 1)     // 65
#define ZPAD 25

union MainSh {
    float tile[WV][KC][LPAD];   // 33.3 KB
    float zbuf[WV][ROWS][ZPAD]; // 25.6 KB
};

__global__ __launch_bounds__(256) void cgc_main(
    const float* __restrict__ x,
    const float* __restrict__ Mg,
    const float* __restrict__ dg,
    const float* __restrict__ bt,
    float* __restrict__ out)
{
    __shared__ MainSh sh;

    const int tid  = threadIdx.x;
    const int w    = tid >> 6;       // wave 0..3
    const int lane = tid & 63;       // row within block
    const int r0   = blockIdx.x * ROWS;
    const int row  = r0 + lane;
    const int lr   = lane >> 3;      // staging base row 0..7
    const int lk   = (lane & 7) * 4; // staging k offset (floats)
    const int kw0  = __builtin_amdgcn_readfirstlane(w * KW);  // uniform!

    const float4* xv = (const float4*)x;
    float4 pre[8];

    auto load_chunk = [&](int c) {
        const int kbase = kw0 + c * KC + lk;
        #pragma unroll
        for (int it = 0; it < 8; ++it) {
            const int rr = r0 + lr + it * 8;
            pre[it] = xv[(rr * II + kbase) >> 2];
        }
    };
    auto store_chunk = [&]() {
        #pragma unroll
        for (int it = 0; it < 8; ++it) {
            const int rr = lr + it * 8;
            sh.tile[w][lk + 0][rr] = pre[it].x;
            sh.tile[w][lk + 1][rr] = pre[it].y;
            sh.tile[w][lk + 2][rr] = pre[it].z;
            sh.tile[w][lk + 3][rr] = pre[it].w;
        }
    };

    float z[NCOL];
    #pragma unroll
    for (int j = 0; j < NCOL; ++j) z[j] = (w == 0) ? dg[j] : 0.0f;

    load_chunk(0);
    store_chunk();
    __builtin_amdgcn_wave_barrier();

    #pragma unroll 1
    for (int c = 0; c < NCHUNK; ++c) {
        if (c + 1 < NCHUNK) load_chunk(c + 1);   // overlap with compute

        const float* Mc = Mg + (kw0 + c * KC) * NCOL;  // wave-uniform base
        #pragma unroll 4
        for (int k = 0; k < KC; ++k) {
            const float xk = sh.tile[w][k][lane];  // ds_read_b32
            const float* Mr = Mc + k * NCOL;       // uniform -> s_load
            #pragma unroll
            for (int j = 0; j < NCOL; ++j)
                z[j] = fmaf(xk, Mr[j], z[j]);      // v_fmac vdst, s, v
        }

        __builtin_amdgcn_wave_barrier();
        if (c + 1 < NCHUNK) {
            store_chunk();
            __builtin_amdgcn_wave_barrier();
        }
    }

    // Cross-wave reduction of z partials (zbuf aliases tile: sync first)
    __syncthreads();
    if (w > 0) {
        #pragma unroll
        for (int j = 0; j < NCOL; ++j) sh.zbuf[w][lane][j] = z[j];
    }
    __syncthreads();

    if (w == 0) {
        #pragma unroll
        for (int ww = 1; ww < WV; ++ww)
            #pragma unroll
            for (int j = 0; j < NCOL; ++j)
                z[j] += sh.zbuf[ww][lane][j];

        // Epilogue: per-task softmax(6) + weighted sum of s-values
        #pragma unroll
        for (int t = 0; t < TT; ++t) {
            const int base = t * NJ;
            float m = z[base + 0];
            #pragma unroll
            for (int j = 1; j < NS; ++j) m = fmaxf(m, z[base + j]);
            float s = 0.0f, o = 0.0f;
            #pragma unroll
            for (int j = 0; j < NS; ++j) {
                const float e = __expf(z[base + j] - m);
                s += e;
                o += e * z[base + NS + j];
            }
            out[t * BB + row] = o / s + bt[t];
        }
    }
}

// ---------------------------------------------------------------------------
extern "C" void kernel_launch(void* const* d_in, const int* in_sizes, int n_in,
                              void* d_out, int out_size, void* d_ws, size_t ws_size,
                              hipStream_t stream)
{
    const float* x  = (const float*)d_in[0];
    const float* Wc = (const float*)d_in[1];
    const float* bc = (const float*)d_in[2];
    const float* Ws = (const float*)d_in[3];
    const float* bs = (const float*)d_in[4];
    const float* Wg = (const float*)d_in[5];
    const float* bg = (const float*)d_in[6];
    const float* Wt = (const float*)d_in[7];
    const float* bt = (const float*)d_in[8];
    float* out = (float*)d_out;

    float* M = (float*)d_ws;            // [II][NCOL]
    float* d = M + II * NCOL;           // [NCOL]

    cgc_precompute<<<dim3(II + 1), dim3(256), 0, stream>>>(
        Wc, bc, Ws, bs, Wg, bg, Wt, M, d);
    cgc_main<<<dim3(BB / ROWS), dim3(256), 0, stream>>>(
        x, M, d, bt, out);
}